// Round 11
// baseline (229.065 us; speedup 1.0000x reference)
//
#include <hip/hip_runtime.h>

// SuperPointMatchesGenerator: B=8, N0=N1=2048 mutual-NN under homography.
// d_out f32, concat: gt_matches0[8,2048] | gt_matches1[8,2048] | min_dist0[8,2048]
//
// R11 = R10 structure with its two bugs fixed (R10 absmax 2049):
//  BUG1: prep pre-doubled BOTH q0 and q1, but each array is rows in one mode
//        and candidates in the other -> hot loop computed (2rx)(2cx) = 4ab.
//        FIX: store plain (X,Y,a2); double once in the block prologue
//        (rx2=fadd(x,x) — exact, commutes with RN => d2 bit-identical to
//        reference (a2+b2)-2ab; proven in R7/R8).
//  BUG2: fused-finalize release chain lacked __syncthreads between the
//        epilogue stores (lanes 0..15) and thread0's ticket atomicAdd ->
//        last block could read 0xAA-poisoned gt0p/gt1.
//        FIX: stores -> __threadfence() -> __syncthreads() -> atomicAdd.
//
// Structure (2 dispatches):
//  prep (128 blocks): reproject kpts0 -> q0=(X,Y,a2), kpts1 -> q1=(x,y,b2); cnt=0.
//  main (2048 blocks x 256): 16 rows/block; mode0 blocks 0..1023 row-argmin
//    (gt0p packed u16 + min_dist f32 -> chunk 2), mode1 blocks col-argmin (gt1).
//    Last block (ticket) gathers gt_matches0/gt_matches1 (race-free gather form
//    of the reference scatter; validity => injectivity).
//
// FP exactness vs numpy-f32 (no FMA contraction, explicit __f*_rn):
//   p_i = (H[i0]*x + H[i1]*y) + H[i2];  X = p0/(p2+1e-8);  a2 = X*X + Y*Y;
//   d2  = (a2 + b2) - 2*ab;  compare max(d2,0); winner e = sqrt(max(d2,0)).
// Keep-first argmin at every level (strict <, ascending index, u64
// (d2bits<<32|idx) min reduction).
//
// ws (full path, ~576KB): q0 f4[16K] | q1 f4[16K] | gt0p u16[16K] | gt1 u16[16K]
// | counter u32. Fallback (ws < needed): R5-proven 64KB brute force, 2 dispatches.

#define SPN 2048
#define SPT 16384
#define RPB 16   // rows per block in main

__device__ __forceinline__ void sp_reproject(const float* __restrict__ T, int b,
                                             float x, float y,
                                             float& X, float& Y, float& S) {
  const float* H = T + b * 9;
  float p0 = __fadd_rn(__fadd_rn(__fmul_rn(H[0], x), __fmul_rn(H[1], y)), H[2]);
  float p1 = __fadd_rn(__fadd_rn(__fmul_rn(H[3], x), __fmul_rn(H[4], y)), H[5]);
  float p2 = __fadd_rn(__fadd_rn(__fmul_rn(H[6], x), __fmul_rn(H[7], y)), H[8]);
  float den = __fadd_rn(p2, 1e-8f);
  X = __fdiv_rn(p0, den);
  Y = __fdiv_rn(p1, den);
  S = __fadd_rn(__fmul_rn(X, X), __fmul_rn(Y, Y));
}

__global__ __launch_bounds__(256) void sp_prep(
    const float2* __restrict__ k0, const float2* __restrict__ k1,
    const float* __restrict__ T, float4* __restrict__ q0, float4* __restrict__ q1,
    unsigned int* __restrict__ cnt) {
  int t = blockIdx.x * 256 + threadIdx.x;
  if (t == 0) *cnt = 0;                     // ticket counter (ws is 0xAA-poisoned)
  if (t < SPT) {
    float2 p = k0[t];
    float X, Y, S;
    sp_reproject(T, t >> 11, p.x, p.y, X, Y, S);
    q0[t] = make_float4(X, Y, S, 0.0f);     // PLAIN (BUG1 fix)
  } else {
    int u = t - SPT;
    float2 p = k1[u];
    float S = __fadd_rn(__fmul_rn(p.x, p.x), __fmul_rn(p.y, p.y));
    q1[u] = make_float4(p.x, p.y, S, 0.0f);
  }
}

__device__ __forceinline__ void sp_row16(
    const float rx2[RPB], const float ry2[RPB], const float rs[RPB],
    float bv[RPB], int bi[RPB], float4 v, int c) {
#pragma unroll
  for (int r = 0; r < RPB; r++) {
    // rows doubled, candidates plain: ab2 == 2*ab bit-exactly
    float ab2 = __fadd_rn(__fmul_rn(rx2[r], v.x), __fmul_rn(ry2[r], v.y));
    float d2 = __fsub_rn(__fadd_rn(rs[r], v.z), ab2);
    float dm = fmaxf(d2, 0.0f);
    if (dm < bv[r]) { bv[r] = dm; bi[r] = c; }   // keep-first (ascending c)
  }
}

__global__ __launch_bounds__(256, 4) void SuperPointMatchesGenerator_56925496541369_kernel(
    const float4* __restrict__ q0, const float4* __restrict__ q1,
    unsigned short* __restrict__ gt0p, unsigned short* __restrict__ gt1,
    unsigned int* __restrict__ cnt, float* __restrict__ out) {
  const bool m1 = blockIdx.x >= (SPT / RPB);      // block-uniform
  const int base = (m1 ? blockIdx.x - SPT / RPB : blockIdx.x) * RPB;
  const int b = base >> 11, cb = b << 11;
  const float4* __restrict__ qr = m1 ? q1 : q0;         // rows (x,y,s)
  const float4* __restrict__ qc = (m1 ? q0 : q1) + cb;  // candidates (x,y,s)

  float rx2[RPB], ry2[RPB], rs[RPB], bv[RPB];
  int bi[RPB];
#pragma unroll
  for (int r = 0; r < RPB; r++) {
    float4 v = qr[base + r];                      // uniform addr -> broadcast
    rx2[r] = __fadd_rn(v.x, v.x);                 // double ROW side only
    ry2[r] = __fadd_rn(v.y, v.y);
    rs[r] = v.z;
    bv[r] = INFINITY; bi[r] = 0;
  }

#pragma unroll 1
  for (int c = threadIdx.x; c < SPN; c += 512) {  // 4 iters, loads hoisted (MLP)
    float4 va = qc[c];
    float4 vb = qc[c + 256];
    sp_row16(rx2, ry2, rs, bv, bi, va, c);        // ascending: c before c+256
    sp_row16(rx2, ry2, rs, bv, bi, vb, c + 256);
  }

  unsigned long long key[RPB];
#pragma unroll
  for (int r = 0; r < RPB; r++)
    key[r] = ((unsigned long long)__float_as_uint(bv[r]) << 32) | (unsigned)bi[r];
#pragma unroll
  for (int off = 32; off > 0; off >>= 1) {
#pragma unroll
    for (int r = 0; r < RPB; r++) {
      unsigned long long o = __shfl_down(key[r], off);
      if (o < key[r]) key[r] = o;
    }
  }
  __shared__ unsigned long long part[4][RPB];
  if ((threadIdx.x & 63) == 0) {
    int w = threadIdx.x >> 6;
#pragma unroll
    for (int r = 0; r < RPB; r++) part[w][r] = key[r];
  }
  __syncthreads();
  if (threadIdx.x < RPB) {
    int r = threadIdx.x;
    unsigned long long k = part[0][r];
#pragma unroll
    for (int w = 1; w < 4; w++)
      if (part[w][r] < k) k = part[w][r];
    int idx = (int)(k & 0x7ffu);
    if (!m1) {
      float e = __fsqrt_rn(__uint_as_float((unsigned)(k >> 32)));
      unsigned short pk = (unsigned short)idx;
      if (e > 3.0f) pk |= 0x8000u;                // strict >, exact fp32
      gt0p[base + r] = pk;
      out[2 * SPT + base + r] = e;                // min_dist0
    } else {
      gt1[base + r] = (unsigned short)idx;
    }
  }

  // ---- fused finalize: last block to take a ticket gathers the outputs ----
  __threadfence();        // release: each storing thread fences its own stores
  __syncthreads();        // BUG2 fix: all stores+fences complete before ticket
  __shared__ unsigned int ticket;
  if (threadIdx.x == 0) ticket = atomicAdd(cnt, 1u);
  __syncthreads();
  if (ticket == 2u * (SPT / RPB) - 1u) {
    __threadfence();                               // acquire all blocks' stores
    for (int t = threadIdx.x; t < SPT; t += 256) {
      int bb = t >> 11, i = t & 2047, cbb = bb << 11;
      unsigned short p0 = gt0p[t];
      int m0 = p0 & 0x7ff;
      bool ok0 = ((p0 & 0x8000u) == 0) && ((int)gt1[cbb + m0] == i);
      out[t] = ok0 ? (float)m0 : -1.0f;            // gt_matches0
      int istar = gt1[t];                          // gather form of the scatter
      unsigned short ps = gt0p[cbb + istar];
      bool ok1 = (((int)(ps & 0x7ff)) == i) && ((ps & 0x8000u) == 0);
      out[SPT + t] = ok1 ? (float)istar : -1.0f;   // gt_matches1
    }
  }
}

// ---------- fallback (R5-proven, 64KB ws, 2 dispatches) ----------
__global__ __launch_bounds__(256) void sp_fb_main(
    const float2* __restrict__ k0, const float2* __restrict__ k1,
    const float* __restrict__ T, unsigned short* __restrict__ gt0p,
    unsigned short* __restrict__ gt1, float* __restrict__ out_mind) {
  const bool mode1 = blockIdx.x >= SPN;
  const int base = (mode1 ? blockIdx.x - SPN : blockIdx.x) * 8;
  const int b = base >> 11, cb = b << 11;
  float rx[8], ry[8], rs[8], bv[8];
  int bi[8];
#pragma unroll
  for (int r = 0; r < 8; r++) { bv[r] = INFINITY; bi[r] = 0; }
  if (!mode1) {
#pragma unroll
    for (int r = 0; r < 8; r++) {
      float2 p = k0[base + r];
      sp_reproject(T, b, p.x, p.y, rx[r], ry[r], rs[r]);
    }
    for (int c = threadIdx.x; c < SPN; c += 256) {
      float2 p = k1[cb + c];
      float b2 = __fadd_rn(__fmul_rn(p.x, p.x), __fmul_rn(p.y, p.y));
#pragma unroll
      for (int r = 0; r < 8; r++) {
        float ab = __fadd_rn(__fmul_rn(rx[r], p.x), __fmul_rn(ry[r], p.y));
        float d2 = __fsub_rn(__fadd_rn(rs[r], b2), __fmul_rn(2.0f, ab));
        float dm = fmaxf(d2, 0.0f);
        if (dm < bv[r]) { bv[r] = dm; bi[r] = c; }
      }
    }
  } else {
#pragma unroll
    for (int r = 0; r < 8; r++) {
      float2 p = k1[base + r];
      rx[r] = p.x; ry[r] = p.y;
      rs[r] = __fadd_rn(__fmul_rn(p.x, p.x), __fmul_rn(p.y, p.y));
    }
    for (int c = threadIdx.x; c < SPN; c += 256) {
      float2 p = k0[cb + c];
      float cx, cy, a2;
      sp_reproject(T, b, p.x, p.y, cx, cy, a2);
#pragma unroll
      for (int r = 0; r < 8; r++) {
        float ab = __fadd_rn(__fmul_rn(rx[r], cx), __fmul_rn(ry[r], cy));
        float d2 = __fsub_rn(__fadd_rn(a2, rs[r]), __fmul_rn(2.0f, ab));
        float dm = fmaxf(d2, 0.0f);
        if (dm < bv[r]) { bv[r] = dm; bi[r] = c; }
      }
    }
  }
  unsigned long long key[8];
#pragma unroll
  for (int r = 0; r < 8; r++)
    key[r] = ((unsigned long long)__float_as_uint(bv[r]) << 32) | (unsigned)bi[r];
#pragma unroll
  for (int off = 32; off > 0; off >>= 1) {
#pragma unroll
    for (int r = 0; r < 8; r++) {
      unsigned long long o = __shfl_down(key[r], off);
      if (o < key[r]) key[r] = o;
    }
  }
  __shared__ unsigned long long part[4][8];
  if ((threadIdx.x & 63) == 0) {
    int w = threadIdx.x >> 6;
#pragma unroll
    for (int r = 0; r < 8; r++) part[w][r] = key[r];
  }
  __syncthreads();
  if (threadIdx.x < 8) {
    int r = threadIdx.x;
    unsigned long long k = part[0][r];
#pragma unroll
    for (int w = 1; w < 4; w++)
      if (part[w][r] < k) k = part[w][r];
    int idx = (int)(k & 0x7ffu);
    if (!mode1) {
      float e = __fsqrt_rn(__uint_as_float((unsigned)(k >> 32)));
      unsigned short pk = (unsigned short)idx;
      if (e > 3.0f) pk |= 0x8000u;
      gt0p[base + r] = pk;
      out_mind[base + r] = e;
    } else {
      gt1[base + r] = (unsigned short)idx;
    }
  }
}

__global__ __launch_bounds__(256) void sp_fb_final(
    const unsigned short* __restrict__ gt0p, const unsigned short* __restrict__ gt1,
    float* __restrict__ out) {
  int t = blockIdx.x * 256 + threadIdx.x;
  if (t >= SPT) return;
  int b = t >> 11, i = t & 2047, cb = b << 11;
  unsigned short p0 = gt0p[t];
  int m0 = p0 & 0x7ff;
  bool ok0 = ((p0 & 0x8000u) == 0) && ((int)gt1[cb + m0] == i);
  out[t] = ok0 ? (float)m0 : -1.0f;
  int istar = gt1[t];
  unsigned short ps = gt0p[cb + istar];
  bool ok1 = (((int)(ps & 0x7ff)) == i) && ((ps & 0x8000u) == 0);
  out[SPT + t] = ok1 ? (float)istar : -1.0f;
}

extern "C" void kernel_launch(void* const* d_in, const int* in_sizes, int n_in,
                              void* d_out, int out_size, void* d_ws, size_t ws_size,
                              hipStream_t stream) {
  (void)in_sizes; (void)n_in; (void)out_size;
  const float2* k0 = (const float2*)d_in[0];
  const float2* k1 = (const float2*)d_in[1];
  const float* T   = (const float*)d_in[2];
  float* out = (float*)d_out;

  const size_t need = (size_t)2 * SPT * sizeof(float4)
                    + (size_t)2 * SPT * sizeof(unsigned short) + 64;
  if (ws_size >= need) {
    float4* q0 = (float4*)d_ws;                          // 256 KB
    float4* q1 = q0 + SPT;                               // 256 KB
    unsigned short* gt0p = (unsigned short*)(q1 + SPT);  // 32 KB
    unsigned short* gt1  = gt0p + SPT;                   // 32 KB
    unsigned int* cnt = (unsigned int*)(gt1 + SPT);      // ticket counter
    sp_prep<<<2 * SPT / 256, 256, 0, stream>>>(k0, k1, T, q0, q1, cnt);
    SuperPointMatchesGenerator_56925496541369_kernel<<<2 * (SPT / RPB), 256, 0, stream>>>(
        q0, q1, gt0p, gt1, cnt, out);
  } else {
    unsigned short* gt0p = (unsigned short*)d_ws;
    unsigned short* gt1  = gt0p + SPT;
    sp_fb_main<<<2 * SPN, 256, 0, stream>>>(k0, k1, T, gt0p, gt1, out + 2 * SPT);
    sp_fb_final<<<SPT / 256, 256, 0, stream>>>(gt0p, gt1, out);
  }
}

// Round 12
// 84.896 us; speedup vs baseline: 2.6982x; 2.6982x over previous
//
#include <hip/hip_runtime.h>

// SuperPointMatchesGenerator: B=8, N0=N1=2048 mutual-NN under homography.
// d_out f32, concat: gt_matches0[8,2048] | gt_matches1[8,2048] | min_dist0[8,2048]
//
// R12 = R9 skeleton (best passing: 82.6us, 3 dispatches, NO fences/atomics)
// + the two fence-free wins proven correct inside R11's main:
//  - 16 rows/block (grid 2048, was 4096): halves waves -> halves prologue,
//    candidate-load and loop overhead per pair.
//  - row-side x2 pre-doubling in the block prologue (9 VALU/pair):
//    rx2=fadd(x,x) exact; fadd(fmul(2rx,cx),fmul(2ry,cy)) == fmul(2,ab)
//    bit-exactly (doubling commutes with round-to-nearest; no overflow here).
//
// LESSON (R11): per-block __threadfence() on the epilogue path = device-scope
// L2 writeback per block -> main went 25us -> 180us (VALUBusy 12%). Fused
// single-kernel finalize is a dead end on multi-XCD CDNA4; keep the separate
// 64-block final dispatch (~2-4us total).
//
// FP exactness vs numpy-f32 (no FMA contraction, explicit __f*_rn):
//   p_i = (H[i0]*x + H[i1]*y) + H[i2];  X = p0/(p2+1e-8);  a2 = X*X + Y*Y;
//   d2  = (a2 + b2) - 2*ab;  compare max(d2,0); winner e = sqrt(max(d2,0)).
// Keep-first argmin at every level (strict <, ascending index, u64
// (d2bits<<32|idx) min reduction).
//
// ws (full path, 576KB): q0 f4[16K] | q1 f4[16K] | gt0p u16[16K] | gt1 u16[16K]
// Fallback (ws < needed): R5-proven 64KB brute force, 2 dispatches.

#define SPN 2048
#define SPT 16384
#define RPB 16   // rows per block in main

__device__ __forceinline__ void sp_reproject(const float* __restrict__ T, int b,
                                             float x, float y,
                                             float& X, float& Y, float& S) {
  const float* H = T + b * 9;
  float p0 = __fadd_rn(__fadd_rn(__fmul_rn(H[0], x), __fmul_rn(H[1], y)), H[2]);
  float p1 = __fadd_rn(__fadd_rn(__fmul_rn(H[3], x), __fmul_rn(H[4], y)), H[5]);
  float p2 = __fadd_rn(__fadd_rn(__fmul_rn(H[6], x), __fmul_rn(H[7], y)), H[8]);
  float den = __fadd_rn(p2, 1e-8f);
  X = __fdiv_rn(p0, den);
  Y = __fdiv_rn(p1, den);
  S = __fadd_rn(__fmul_rn(X, X), __fmul_rn(Y, Y));
}

__global__ __launch_bounds__(256) void sp_prep(
    const float2* __restrict__ k0, const float2* __restrict__ k1,
    const float* __restrict__ T, float4* __restrict__ q0, float4* __restrict__ q1) {
  int t = blockIdx.x * 256 + threadIdx.x;
  if (t < SPT) {
    float2 p = k0[t];
    float X, Y, S;
    sp_reproject(T, t >> 11, p.x, p.y, X, Y, S);
    q0[t] = make_float4(X, Y, S, 0.0f);
  } else {
    int u = t - SPT;
    float2 p = k1[u];
    float S = __fadd_rn(__fmul_rn(p.x, p.x), __fmul_rn(p.y, p.y));
    q1[u] = make_float4(p.x, p.y, S, 0.0f);
  }
}

__device__ __forceinline__ void sp_row16(
    const float rx2[RPB], const float ry2[RPB], const float rs[RPB],
    float bv[RPB], int bi[RPB], float4 v, int c) {
#pragma unroll
  for (int r = 0; r < RPB; r++) {
    // rows doubled, candidates plain: ab2 == 2*ab bit-exactly
    float ab2 = __fadd_rn(__fmul_rn(rx2[r], v.x), __fmul_rn(ry2[r], v.y));
    float d2 = __fsub_rn(__fadd_rn(rs[r], v.z), ab2);
    float dm = fmaxf(d2, 0.0f);
    if (dm < bv[r]) { bv[r] = dm; bi[r] = c; }   // keep-first (ascending c)
  }
}

__global__ __launch_bounds__(256, 4) void SuperPointMatchesGenerator_56925496541369_kernel(
    const float4* __restrict__ q0, const float4* __restrict__ q1,
    unsigned short* __restrict__ gt0p, unsigned short* __restrict__ gt1,
    float* __restrict__ out_mind) {
  const bool m1 = blockIdx.x >= (SPT / RPB);      // block-uniform
  const int base = (m1 ? blockIdx.x - SPT / RPB : blockIdx.x) * RPB;
  const int b = base >> 11, cb = b << 11;
  const float4* __restrict__ qr = m1 ? q1 : q0;         // rows (x,y,s)
  const float4* __restrict__ qc = (m1 ? q0 : q1) + cb;  // candidates (x,y,s)

  float rx2[RPB], ry2[RPB], rs[RPB], bv[RPB];
  int bi[RPB];
#pragma unroll
  for (int r = 0; r < RPB; r++) {
    float4 v = qr[base + r];                      // uniform addr -> broadcast
    rx2[r] = __fadd_rn(v.x, v.x);                 // double ROW side only
    ry2[r] = __fadd_rn(v.y, v.y);
    rs[r] = v.z;
    bv[r] = INFINITY; bi[r] = 0;
  }

#pragma unroll 1
  for (int c = threadIdx.x; c < SPN; c += 512) {  // 4 iters, loads hoisted (MLP)
    float4 va = qc[c];
    float4 vb = qc[c + 256];
    sp_row16(rx2, ry2, rs, bv, bi, va, c);        // ascending: c before c+256
    sp_row16(rx2, ry2, rs, bv, bi, vb, c + 256);
  }

  unsigned long long key[RPB];
#pragma unroll
  for (int r = 0; r < RPB; r++)
    key[r] = ((unsigned long long)__float_as_uint(bv[r]) << 32) | (unsigned)bi[r];
#pragma unroll
  for (int off = 32; off > 0; off >>= 1) {
#pragma unroll
    for (int r = 0; r < RPB; r++) {
      unsigned long long o = __shfl_down(key[r], off);
      if (o < key[r]) key[r] = o;
    }
  }
  __shared__ unsigned long long part[4][RPB];
  if ((threadIdx.x & 63) == 0) {
    int w = threadIdx.x >> 6;
#pragma unroll
    for (int r = 0; r < RPB; r++) part[w][r] = key[r];
  }
  __syncthreads();                                 // single barrier
  if (threadIdx.x < RPB) {
    int r = threadIdx.x;
    unsigned long long k = part[0][r];
#pragma unroll
    for (int w = 1; w < 4; w++)
      if (part[w][r] < k) k = part[w][r];
    int idx = (int)(k & 0x7ffu);
    if (!m1) {
      float e = __fsqrt_rn(__uint_as_float((unsigned)(k >> 32)));
      unsigned short pk = (unsigned short)idx;
      if (e > 3.0f) pk |= 0x8000u;                 // strict >, exact fp32
      gt0p[base + r] = pk;
      out_mind[base + r] = e;                      // min_dist0
    } else {
      gt1[base + r] = (unsigned short)idx;
    }
  }
}

__global__ __launch_bounds__(256) void SuperPointMatchesGenerator_56925496541369_final(
    const unsigned short* __restrict__ gt0p, const unsigned short* __restrict__ gt1,
    float* __restrict__ out) {
  int t = blockIdx.x * 256 + threadIdx.x;
  if (t >= SPT) return;
  int b = t >> 11, i = t & 2047, cb = b << 11;

  unsigned short p0 = gt0p[t];
  int m0 = p0 & 0x7ff;
  bool ok0 = ((p0 & 0x8000u) == 0) && ((int)gt1[cb + m0] == i);
  out[t] = ok0 ? (float)m0 : -1.0f;

  int istar = gt1[t];                              // gather form of the scatter
  unsigned short ps = gt0p[cb + istar];
  bool ok1 = (((int)(ps & 0x7ff)) == i) && ((ps & 0x8000u) == 0);
  out[SPT + t] = ok1 ? (float)istar : -1.0f;
}

// ---------- fallback (R5-proven, 64KB ws, 2 dispatches) ----------
__global__ __launch_bounds__(256) void sp_fb_main(
    const float2* __restrict__ k0, const float2* __restrict__ k1,
    const float* __restrict__ T, unsigned short* __restrict__ gt0p,
    unsigned short* __restrict__ gt1, float* __restrict__ out_mind) {
  const bool mode1 = blockIdx.x >= SPN;
  const int base = (mode1 ? blockIdx.x - SPN : blockIdx.x) * 8;
  const int b = base >> 11, cb = b << 11;
  float rx[8], ry[8], rs[8], bv[8];
  int bi[8];
#pragma unroll
  for (int r = 0; r < 8; r++) { bv[r] = INFINITY; bi[r] = 0; }
  if (!mode1) {
#pragma unroll
    for (int r = 0; r < 8; r++) {
      float2 p = k0[base + r];
      sp_reproject(T, b, p.x, p.y, rx[r], ry[r], rs[r]);
    }
    for (int c = threadIdx.x; c < SPN; c += 256) {
      float2 p = k1[cb + c];
      float b2 = __fadd_rn(__fmul_rn(p.x, p.x), __fmul_rn(p.y, p.y));
#pragma unroll
      for (int r = 0; r < 8; r++) {
        float ab = __fadd_rn(__fmul_rn(rx[r], p.x), __fmul_rn(ry[r], p.y));
        float d2 = __fsub_rn(__fadd_rn(rs[r], b2), __fmul_rn(2.0f, ab));
        float dm = fmaxf(d2, 0.0f);
        if (dm < bv[r]) { bv[r] = dm; bi[r] = c; }
      }
    }
  } else {
#pragma unroll
    for (int r = 0; r < 8; r++) {
      float2 p = k1[base + r];
      rx[r] = p.x; ry[r] = p.y;
      rs[r] = __fadd_rn(__fmul_rn(p.x, p.x), __fmul_rn(p.y, p.y));
    }
    for (int c = threadIdx.x; c < SPN; c += 256) {
      float2 p = k0[cb + c];
      float cx, cy, a2;
      sp_reproject(T, b, p.x, p.y, cx, cy, a2);
#pragma unroll
      for (int r = 0; r < 8; r++) {
        float ab = __fadd_rn(__fmul_rn(rx[r], cx), __fmul_rn(ry[r], cy));
        float d2 = __fsub_rn(__fadd_rn(a2, rs[r]), __fmul_rn(2.0f, ab));
        float dm = fmaxf(d2, 0.0f);
        if (dm < bv[r]) { bv[r] = dm; bi[r] = c; }
      }
    }
  }
  unsigned long long key[8];
#pragma unroll
  for (int r = 0; r < 8; r++)
    key[r] = ((unsigned long long)__float_as_uint(bv[r]) << 32) | (unsigned)bi[r];
#pragma unroll
  for (int off = 32; off > 0; off >>= 1) {
#pragma unroll
    for (int r = 0; r < 8; r++) {
      unsigned long long o = __shfl_down(key[r], off);
      if (o < key[r]) key[r] = o;
    }
  }
  __shared__ unsigned long long part[4][8];
  if ((threadIdx.x & 63) == 0) {
    int w = threadIdx.x >> 6;
#pragma unroll
    for (int r = 0; r < 8; r++) part[w][r] = key[r];
  }
  __syncthreads();
  if (threadIdx.x < 8) {
    int r = threadIdx.x;
    unsigned long long k = part[0][r];
#pragma unroll
    for (int w = 1; w < 4; w++)
      if (part[w][r] < k) k = part[w][r];
    int idx = (int)(k & 0x7ffu);
    if (!mode1) {
      float e = __fsqrt_rn(__uint_as_float((unsigned)(k >> 32)));
      unsigned short pk = (unsigned short)idx;
      if (e > 3.0f) pk |= 0x8000u;
      gt0p[base + r] = pk;
      out_mind[base + r] = e;
    } else {
      gt1[base + r] = (unsigned short)idx;
    }
  }
}

extern "C" void kernel_launch(void* const* d_in, const int* in_sizes, int n_in,
                              void* d_out, int out_size, void* d_ws, size_t ws_size,
                              hipStream_t stream) {
  (void)in_sizes; (void)n_in; (void)out_size;
  const float2* k0 = (const float2*)d_in[0];
  const float2* k1 = (const float2*)d_in[1];
  const float* T   = (const float*)d_in[2];
  float* out = (float*)d_out;

  const size_t need = (size_t)2 * SPT * sizeof(float4)
                    + (size_t)2 * SPT * sizeof(unsigned short);
  if (ws_size >= need) {
    float4* q0 = (float4*)d_ws;                          // 256 KB
    float4* q1 = q0 + SPT;                               // 256 KB
    unsigned short* gt0p = (unsigned short*)(q1 + SPT);  // 32 KB
    unsigned short* gt1  = gt0p + SPT;                   // 32 KB
    sp_prep<<<2 * SPT / 256, 256, 0, stream>>>(k0, k1, T, q0, q1);
    SuperPointMatchesGenerator_56925496541369_kernel<<<2 * (SPT / RPB), 256, 0, stream>>>(
        q0, q1, gt0p, gt1, out + 2 * SPT);
    SuperPointMatchesGenerator_56925496541369_final<<<SPT / 256, 256, 0, stream>>>(
        gt0p, gt1, out);
  } else {
    unsigned short* gt0p = (unsigned short*)d_ws;
    unsigned short* gt1  = gt0p + SPT;
    sp_fb_main<<<2 * SPN, 256, 0, stream>>>(k0, k1, T, gt0p, gt1, out + 2 * SPT);
    SuperPointMatchesGenerator_56925496541369_final<<<SPT / 256, 256, 0, stream>>>(
        gt0p, gt1, out);
  }
}